// Round 6
// baseline (251.321 us; speedup 1.0000x reference)
//
#include <hip/hip_runtime.h>
#include <hip/hip_fp16.h>
#include <stdint.h>

#define NCTX 5952
#define NHEAD 16

typedef _Float16 f16x8 __attribute__((ext_vector_type(8)));
typedef _Float16 f16x4 __attribute__((ext_vector_type(4)));
typedef float    f32x4 __attribute__((ext_vector_type(4)));

typedef const __attribute__((address_space(1))) void* gp1;
typedef __attribute__((address_space(3))) void* lp3;

__device__ __forceinline__ f32x4 mfma16(f16x8 a, f16x8 b, f32x4 c) {
    return __builtin_amdgcn_mfma_f32_16x16x32_f16(a, b, c, 0, 0, 0);
}

// per-seq tables: lengths {512,576,640,704,768,832,896,1024}
__device__ const int kQT[9]    = {0, 4, 9, 14, 20, 26, 33, 40, 48}; // cum 128-row q-tiles
__device__ const int kBASE8[8] = {0, 512, 1088, 1728, 2432, 3200, 4032, 4928};
__device__ const int kLEN[8]   = {512, 576, 640, 704, 768, 832, 896, 1024};

// ---- fused pre-split: fp32 -> f16 hi/lo plain row-major arrays ----
__global__ __launch_bounds__(256) void presplit_all(
    const float* __restrict__ x,
    const float* __restrict__ Wq, const float* __restrict__ Wk,
    const float* __restrict__ Wv, const float* __restrict__ Wo,
    _Float16* __restrict__ Ah, _Float16* __restrict__ Al,
    _Float16* __restrict__ Wh, _Float16* __restrict__ Wl)
{
    constexpr int NA = NCTX * 128 / 256;   // 2976
    const int bid = blockIdx.x;
    const float* src;
    _Float16 *dh, *dl;
    size_t off;
    if (bid < NA) {
        int idx = bid * 256 + threadIdx.x;
        int m = idx >> 7, k8 = (idx & 127) << 3;
        src = x + (size_t)m * 1024 + k8;
        off = (size_t)m * 1024 + k8;
        dh = Ah; dl = Al;
    } else {
        int idx = (bid - NA) * 256 + threadIdx.x;
        int n = idx >> 7, k8 = (idx & 127) << 3;
        const float* s = (n < 1024) ? Wq : (n < 2048) ? Wk : (n < 3072) ? Wv : Wo;
        src = s + (size_t)(n & 1023) * 1024 + k8;
        off = (size_t)n * 1024 + k8;
        dh = Wh; dl = Wl;
    }
    f16x8 hi, lo;
    #pragma unroll
    for (int e = 0; e < 8; ++e) {
        float v = src[e];
        _Float16 h = (_Float16)v;
        hi[e] = h; lo[e] = (_Float16)(v - (float)h);
    }
    *(f16x8*)&dh[off] = hi;
    *(f16x8*)&dl[off] = lo;
}

// ---- 3-pairing split GEMM: C = Ah*Bh + Ah*Bl + Al*Bh, K=1024, BK=32 ----
// BM=192; MODE 0: BN=192, grid 31x16=496; MODE 1: BN=128, grid 31x8=248.
// 3 LDS buffers; software-pipelined phases: each MFMA cluster overlaps the
// NEXT cluster's ds_reads; ONE barrier + counted vmcnt per K-step.
// Register ping-pong (2-step unroll) carries ah/bh across the barrier.
template <int MODE>
__global__ __launch_bounds__(512) void gemm3p(
    const _Float16* __restrict__ Ahg, const _Float16* __restrict__ Alg,
    const _Float16* __restrict__ Whg, const _Float16* __restrict__ Wlg,
    const float* __restrict__ bq, const float* __restrict__ bv, const float* __restrict__ bo,
    _Float16* __restrict__ qh, _Float16* __restrict__ kh, _Float16* __restrict__ vt,
    float* __restrict__ outp)
{
    constexpr int BM   = 192;
    constexpr int BN   = (MODE == 0) ? 192 : 128;
    constexpr int MI   = 6;                 // m-frags/wave (96 rows)
    constexpr int NF   = BN / 64;           // n-frags/wave
    constexpr int NTg  = (MODE == 0) ? 16 : 8;
    constexpr int nA   = 12;
    constexpr int nB   = BN / 16;
    constexpr int SPW  = (2 * nA + 2 * nB) / 8;   // stage instrs per wave: 6 / 5
    constexpr int ABYT = BM * 64;
    constexpr int BBYT = BN * 64;
    constexpr int BUF  = 2 * ABYT + 2 * BBYT;
    constexpr int T    = 32;
    constexpr int W0   = (MODE == 0) ? 0 : 3072;

    __shared__ __align__(16) char lds[3 * BUF];

    int bid = blockIdx.x;
    constexpr int cpx = (31 * NTg) / 8;
    bid = (bid & 7) * cpx + (bid >> 3);     // bijective XCD swizzle
    const int mt = bid / NTg, nt = bid % NTg;
    const int m0 = mt * BM, n0 = nt * BN;
    const int tid = threadIdx.x;
    const int w = tid >> 6, l = tid & 63;
    const int ls = l >> 4, lq = l & 15;
    const int wm = w >> 2, wn = w & 3;

    // stage sources: lane fetches logical granule (j ^ ((row>>1)&3)) so the LDS
    // tile ends up granule-swizzled while the DMA dest stays linear (rule 21).
    const char* gsrc[SPW];
    int         ldst[SPW];
    #pragma unroll
    for (int s = 0; s < SPW; ++s) {
        int f = w * SPW + s;
        const _Float16* base; int row; int aoff;
        if (f < nA)               { base = Ahg; row = m0 + f * 16;                 aoff = f * 1024; }
        else if (f < 2 * nA)      { base = Alg; row = m0 + (f - nA) * 16;          aoff = ABYT + (f - nA) * 1024; }
        else if (f < 2 * nA + nB) { base = Whg; row = W0 + n0 + (f - 2 * nA) * 16; aoff = 2 * ABYT + (f - 2 * nA) * 1024; }
        else                      { base = Wlg; row = W0 + n0 + (f - 2 * nA - nB) * 16;
                                    aoff = 2 * ABYT + BBYT + (f - 2 * nA - nB) * 1024; }
        row += (l >> 2);
        gsrc[s] = (const char*)base + (size_t)row * 2048 + 16 * ((l & 3) ^ ((row >> 1) & 3));
        ldst[s] = aoff;
    }
    auto STG = [&](int buf, int t2, int s) {
        __builtin_amdgcn_global_load_lds((gp1)(gsrc[s] + (size_t)t2 * 64),
                                         (lp3)(lds + buf * BUF + ldst[s]), 16, 0, 0);
    };

    // fragment LDS offsets (lane-constant); storage granule = ls ^ ((row>>1)&3)
    int aoA[MI], aoB[NF];
    #pragma unroll
    for (int i = 0; i < MI; ++i) {
        int r = wm * 96 + i * 16 + lq;
        aoA[i] = r * 64 + 16 * (ls ^ ((r >> 1) & 3));
    }
    #pragma unroll
    for (int j = 0; j < NF; ++j) {
        int r = wn * (BN / 4) + j * 16 + lq;
        aoB[j] = 2 * ABYT + r * 64 + 16 * (ls ^ ((r >> 1) & 3));
    }

    f32x4 acc[MI][NF] = {};
    f16x8 ahA[MI], bhA[NF], ahB[MI], bhB[NF];

    // prologue: stage tiles 0,1 into bufs 0,1; wait tile0; read its h-frags
    #pragma unroll
    for (int pt = 0; pt < 2; ++pt)
        #pragma unroll
        for (int s = 0; s < SPW; ++s) STG(pt, pt, s);
    if constexpr (SPW == 6) asm volatile("s_waitcnt vmcnt(6)" ::: "memory");
    else                    asm volatile("s_waitcnt vmcnt(5)" ::: "memory");
    __builtin_amdgcn_s_barrier();
    asm volatile("" ::: "memory");
    #pragma unroll
    for (int i = 0; i < MI; ++i) ahA[i] = *(const f16x8*)(lds + aoA[i]);
    #pragma unroll
    for (int j = 0; j < NF; ++j) bhA[j] = *(const f16x8*)(lds + aoB[j]);

    // one K-step; consumes (ahC,bhC), preloads (ahN,bhN) for the next step
    auto STEP = [&](int t, int cb, int nb, int pb,
                    f16x8 (&ahC)[MI], f16x8 (&bhC)[NF],
                    f16x8 (&ahN)[MI], f16x8 (&bhN)[NF]) {
        const char* cbp = lds + cb * BUF;
        const char* nbp = lds + nb * BUF;
        if (t + 2 < T)
            #pragma unroll
            for (int s = 0; s < SPW; ++s) STG(pb, t + 2, s);
        f16x8 bl[NF], al[MI];
        // P0: read bl (for P1) under MFMA ah*bh
        #pragma unroll
        for (int j = 0; j < NF; ++j) bl[j] = *(const f16x8*)(cbp + aoB[j] + BBYT);
        __builtin_amdgcn_s_setprio(1);
        #pragma unroll
        for (int i = 0; i < MI; ++i)
            #pragma unroll
            for (int j = 0; j < NF; ++j)
                acc[i][j] = mfma16(ahC[i], bhC[j], acc[i][j]);
        __builtin_amdgcn_s_setprio(0);
        // P1: read al (for P2) under MFMA ah*bl
        #pragma unroll
        for (int i = 0; i < MI; ++i) al[i] = *(const f16x8*)(cbp + aoA[i] + ABYT);
        __builtin_amdgcn_s_setprio(1);
        #pragma unroll
        for (int i = 0; i < MI; ++i)
            #pragma unroll
            for (int j = 0; j < NF; ++j)
                acc[i][j] = mfma16(ahC[i], bl[j], acc[i][j]);
        __builtin_amdgcn_s_setprio(0);
        // step sync: own tile t+1 loads done (counted), own cb reads drained;
        // barrier makes both true block-wide -> buf pb free, buf nb readable
        if (t + 2 < T) {
            if constexpr (SPW == 6) asm volatile("s_waitcnt vmcnt(6) lgkmcnt(0)" ::: "memory");
            else                    asm volatile("s_waitcnt vmcnt(5) lgkmcnt(0)" ::: "memory");
        } else if (t + 1 < T) {
            asm volatile("s_waitcnt vmcnt(0) lgkmcnt(0)" ::: "memory");
        } else {
            asm volatile("s_waitcnt lgkmcnt(0)" ::: "memory");
        }
        __builtin_amdgcn_s_barrier();
        asm volatile("" ::: "memory");   // pin next-buffer reads below barrier
        // P2: read next step's h-frags (from nb) under MFMA al*bh
        if (t + 1 < T) {
            #pragma unroll
            for (int i = 0; i < MI; ++i) ahN[i] = *(const f16x8*)(nbp + aoA[i]);
            #pragma unroll
            for (int j = 0; j < NF; ++j) bhN[j] = *(const f16x8*)(nbp + aoB[j]);
        }
        __builtin_amdgcn_s_setprio(1);
        #pragma unroll
        for (int i = 0; i < MI; ++i)
            #pragma unroll
            for (int j = 0; j < NF; ++j)
                acc[i][j] = mfma16(al[i], bhC[j], acc[i][j]);
        __builtin_amdgcn_s_setprio(0);
    };

    int cb = 0, nb = 1, pb = 2;
    #pragma unroll 1
    for (int t = 0; t < T; t += 2) {
        STEP(t,     cb, nb, pb, ahA, bhA, ahB, bhB);
        { int tmp = cb; cb = nb; nb = pb; pb = tmp; }
        STEP(t + 1, cb, nb, pb, ahB, bhB, ahA, bhA);
        { int tmp = cb; cb = nb; nb = pb; pb = tmp; }
    }

    // C/D layout: col = lane&15 (-> n), row = (lane>>4)*4 + reg (-> m)
    #pragma unroll
    for (int i = 0; i < MI; ++i)
        #pragma unroll
        for (int j = 0; j < NF; ++j) {
            const int mb = m0 + wm * 96 + i * 16 + 4 * ls;
            const int n  = n0 + wn * (BN / 4) + j * 16 + lq;
            if (MODE == 0) {
                const int which = n >> 10, nn = n & 1023;
                const int hh = nn >> 6, dd = nn & 63;
                if (which == 2) {
                    f16x4 vv;
                    #pragma unroll
                    for (int r = 0; r < 4; ++r) vv[r] = (_Float16)(acc[i][j][r] + bv[nn]);
                    *(f16x4*)&vt[((size_t)hh * 64 + dd) * NCTX + mb] = vv;   // d-major
                } else if (which == 0) {
                    #pragma unroll
                    for (int r = 0; r < 4; ++r)
                        qh[((size_t)hh * NCTX + mb + r) * 64 + dd] = (_Float16)(acc[i][j][r] + bq[nn]);
                } else {
                    #pragma unroll
                    for (int r = 0; r < 4; ++r)
                        kh[((size_t)hh * NCTX + mb + r) * 64 + dd] = (_Float16)acc[i][j][r];
                }
            } else {
                #pragma unroll
                for (int r = 0; r < 4; ++r)
                    outp[(size_t)(mb + r) * 1024 + n] = acc[i][j][r] + bo[n];
            }
        }
}

// ---- flash attention (no-max), 4 waves x 32 q-rows per 128-row tile ----
__global__ __launch_bounds__(256) void attn_kernel(
    const _Float16* __restrict__ qh, const _Float16* __restrict__ kh,
    const _Float16* __restrict__ vt,
    _Float16* __restrict__ Ahc, _Float16* __restrict__ Alc)
{
    __shared__ alignas(16) _Float16 P[4][2][16][64];
    const int bid = blockIdx.x;
    const int h = bid & 15, t = bid >> 4;
    int b = 0;
    while (t >= kQT[b + 1]) ++b;
    const int kbase = kBASE8[b];
    const int L = kLEN[b];
    const int w = threadIdx.x >> 6, l = threadIdx.x & 63;
    const int ls = l >> 4, lq = l & 15;
    const int q0l = (t - kQT[b]) * 128 + w * 32;
    if (q0l >= L) return;          // tail waves of ragged tiles; no barriers below
    const int q0 = kbase + q0l;

    f16x8 qf[2][2];
    #pragma unroll
    for (int qg = 0; qg < 2; ++qg) {
        const _Float16* qp = qh + ((size_t)h * NCTX + q0 + qg * 16 + lq) * 64 + ls * 8;
        qf[qg][0] = *(const f16x8*)qp;
        qf[qg][1] = *(const f16x8*)(qp + 32);
    }
    const _Float16* kb = kh + (size_t)h * NCTX * 64;
    const _Float16* vb = vt + (size_t)h * 64 * NCTX;

    f32x4 acc[2][4] = {};
    float lsum[2] = {0.f, 0.f};

    for (int kv = 0; kv < L; kv += 64) {
        f32x4 s[2][4];
        __builtin_amdgcn_s_setprio(1);
        #pragma unroll
        for (int g = 0; g < 4; ++g) {
            const _Float16* kp = kb + (size_t)(kbase + kv + g * 16 + lq) * 64 + ls * 8;
            f16x8 kf0 = *(const f16x8*)kp;
            f16x8 kf1 = *(const f16x8*)(kp + 32);
            #pragma unroll
            for (int qg = 0; qg < 2; ++qg) {
                f32x4 z = {};
                z = mfma16(kf0, qf[qg][0], z);
                z = mfma16(kf1, qf[qg][1], z);
                s[qg][g] = z;   // S^T: row = key, col = q = lane&15
            }
        }
        __builtin_amdgcn_s_setprio(0);
        #pragma unroll
        for (int qg = 0; qg < 2; ++qg) {
            float tsum = 0.f;
            #pragma unroll
            for (int g = 0; g < 4; ++g) {
                f16x4 ph;
                #pragma unroll
                for (int r = 0; r < 4; ++r) {
                    float pv = __expf(s[qg][g][r] * 0.125f);
                    tsum += pv;
                    ph[r] = (_Float16)pv;
                }
                int gi = 2 * g + (ls >> 1);
                *(f16x4*)&P[w][qg][lq][(((gi ^ (lq & 7)) << 3) | ((ls & 1) << 2))] = ph;
            }
            tsum += __shfl_xor(tsum, 16, 64);
            tsum += __shfl_xor(tsum, 32, 64);
            lsum[qg] += tsum;
        }
        __builtin_amdgcn_s_setprio(1);
        #pragma unroll
        for (int c = 0; c < 2; ++c) {
            f16x8 pf[2];
            #pragma unroll
            for (int qg = 0; qg < 2; ++qg)
                pf[qg] = *(const f16x8*)&P[w][qg][lq][((4 * c + ls) ^ (lq & 7)) << 3];
            #pragma unroll
            for (int dg = 0; dg < 4; ++dg) {
                const _Float16* vp = vb + (size_t)(dg * 16 + lq) * NCTX + kbase + kv + c * 32 + ls * 8;
                f16x8 vf = *(const f16x8*)vp;
                #pragma unroll
                for (int qg = 0; qg < 2; ++qg)
                    acc[qg][dg] = mfma16(vf, pf[qg], acc[qg][dg]);
            }
        }
        __builtin_amdgcn_s_setprio(0);
    }

    #pragma unroll
    for (int qg = 0; qg < 2; ++qg) {
        const float inv = 1.f / lsum[qg];
        const int m = q0 + qg * 16 + lq;
        _Float16* rh = Ahc + (size_t)m * 1024 + h * 64;
        _Float16* rl = Alc + (size_t)m * 1024 + h * 64;
        #pragma unroll
        for (int dg = 0; dg < 4; ++dg) {
            f16x4 ch, cl;
            #pragma unroll
            for (int r = 0; r < 4; ++r) {
                float v = acc[qg][dg][r] * inv;
                _Float16 hh = (_Float16)v;
                ch[r] = hh; cl[r] = (_Float16)(v - (float)hh);
            }
            *(f16x4*)(rh + dg * 16 + 4 * ls) = ch;
            *(f16x4*)(rl + dg * 16 + 4 * ls) = cl;
        }
    }
}

extern "C" void kernel_launch(void* const* d_in, const int* in_sizes, int n_in,
                              void* d_out, int out_size, void* d_ws, size_t ws_size,
                              hipStream_t stream)
{
    const float* x  = (const float*)d_in[0];
    const float* Wq = (const float*)d_in[1];
    const float* bq = (const float*)d_in[2];
    const float* Wk = (const float*)d_in[3];
    const float* Wv = (const float*)d_in[4];
    const float* bv = (const float*)d_in[5];
    const float* Wo = (const float*)d_in[6];
    const float* bo = (const float*)d_in[7];
    float* out = (float*)d_out;

    char* p = (char*)d_ws;
    _Float16* Ah  = (_Float16*)p; p += (size_t)NCTX * 1024 * 2;
    _Float16* Al  = (_Float16*)p; p += (size_t)NCTX * 1024 * 2;
    _Float16* Wh  = (_Float16*)p; p += (size_t)4096 * 1024 * 2;
    _Float16* Wl  = (_Float16*)p; p += (size_t)4096 * 1024 * 2;
    _Float16* qh  = (_Float16*)p; p += (size_t)NHEAD * NCTX * 64 * 2;
    _Float16* kh  = (_Float16*)p; p += (size_t)NHEAD * NCTX * 64 * 2;
    _Float16* vt  = (_Float16*)p; p += (size_t)NHEAD * NCTX * 64 * 2;
    _Float16* Ahc = (_Float16*)p; p += (size_t)NCTX * 1024 * 2;
    _Float16* Alc = (_Float16*)p; p += (size_t)NCTX * 1024 * 2;

    presplit_all<<<dim3(NCTX * 128 / 256 + 4096 * 128 / 256), 256, 0, stream>>>(
        x, Wq, Wk, Wv, Wo, Ah, Al, Wh, Wl);
    gemm3p<0><<<dim3(31 * 16), 512, 0, stream>>>(Ah, Al, Wh, Wl, bq, bv, nullptr,
                                                 qh, kh, vt, nullptr);
    attn_kernel<<<dim3(48 * 16), 256, 0, stream>>>(qh, kh, vt, Ahc, Alc);
    gemm3p<1><<<dim3(31 * 8), 512, 0, stream>>>(Ahc, Alc, Wh, Wl, nullptr, nullptr, bo,
                                                nullptr, nullptr, nullptr, out);
}